// Round 6
// baseline (560.976 us; speedup 1.0000x reference)
//
#include <hip/hip_runtime.h>

// ---------------------------------------------------------------------------
// GCN forward, bf16 activations / fp32 weights+accum.
// CSR build via bucketed radix (bucket = dst>>9, 512 nodes/bucket), with
// per-node edge lists PADDED to a multiple of 16 using sentinel src=N
// (dis[N]=0 -> zero contribution). Aggregate inner loop is branch-free with
// 4 gathers in flight. GEMMs: register-blocked outer-product fp32.
// ---------------------------------------------------------------------------

__device__ __forceinline__ unsigned short f2bf(float f) {
    unsigned int u = __builtin_bit_cast(unsigned int, f);
    u = (u + 0x7FFFu + ((u >> 16) & 1u)) >> 16;
    return (unsigned short)u;
}
__device__ __forceinline__ float bf2f(unsigned int lo16) {
    unsigned int v = lo16 << 16;
    return __builtin_bit_cast(float, v);
}
__device__ __forceinline__ void cvt8(const uint4& v, float* f) {
    f[0] = bf2f(v.x & 0xFFFFu); f[1] = bf2f(v.x >> 16);
    f[2] = bf2f(v.y & 0xFFFFu); f[3] = bf2f(v.y >> 16);
    f[4] = bf2f(v.z & 0xFFFFu); f[5] = bf2f(v.z >> 16);
    f[6] = bf2f(v.w & 0xFFFFu); f[7] = bf2f(v.w >> 16);
}
// 1-op-per-element bf16x2 -> {lo,hi} floats, then acc += f * c
__device__ __forceinline__ void macc2(float& aLo, float& aHi, unsigned int d, float c) {
    float lo = __builtin_bit_cast(float, d << 16);
    float hi = __builtin_bit_cast(float, d & 0xFFFF0000u);
    aLo += lo * c;
    aHi += hi * c;
}
__device__ __forceinline__ void macc8(float* acc, const uint4& v, float c) {
    macc2(acc[0], acc[1], v.x, c);
    macc2(acc[2], acc[3], v.y, c);
    macc2(acc[4], acc[5], v.z, c);
    macc2(acc[6], acc[7], v.w, c);
}

// --- A1: bucket histogram (bucket = dst >> 9) ---
__global__ __launch_bounds__(256) void bucket_hist_kernel(const int* __restrict__ dst,
                                                          int* __restrict__ bcount, int E) {
    __shared__ int h[256];
    int t = threadIdx.x;
    h[t] = 0;
    __syncthreads();
    int base = blockIdx.x * 4096;
#pragma unroll
    for (int i = 0; i < 16; ++i) {
        int e = base + t + i * 256;
        if (e < E) atomicAdd(&h[dst[e] >> 9], 1);
    }
    __syncthreads();
    if (h[t] > 0) atomicAdd(&bcount[t], h[t]);
}

__global__ void bucket_scan_kernel(const int* __restrict__ bcount, int* __restrict__ bstart,
                                   float* __restrict__ dis, int NB, int N) {
    __shared__ int s[256];
    int t = threadIdx.x;
    int v = (t < NB) ? bcount[t] : 0;
    s[t] = v;
    __syncthreads();
    for (int off = 1; off < 256; off <<= 1) {
        int tmp = 0;
        if (t >= off) tmp = s[t - off];
        __syncthreads();
        s[t] += tmp;
        __syncthreads();
    }
    bstart[t] = s[t] - v;
    if (t == 255) bstart[256] = s[255];
    if (t == 0) dis[N] = 0.f;   // sentinel row: zero coefficient
}

// --- A2: stage packed (src | local_dst<<17) into bucket windows ---
__global__ __launch_bounds__(256) void bucket_scatter_kernel(const int* __restrict__ src,
                                                             const int* __restrict__ dst,
                                                             const int* __restrict__ bstart,
                                                             int* __restrict__ bfill,
                                                             unsigned int* __restrict__ stage,
                                                             int E) {
    __shared__ int hist[256];
    __shared__ int abase[256];
    int t = threadIdx.x;
    hist[t] = 0;
    __syncthreads();
    int base = blockIdx.x * 4096;
#pragma unroll
    for (int i = 0; i < 16; ++i) {
        int e = base + t + i * 256;
        if (e < E) atomicAdd(&hist[dst[e] >> 9], 1);
    }
    __syncthreads();
    if (hist[t] > 0) {
        int r = atomicAdd(&bfill[t], hist[t]);
        abase[t] = bstart[t] + r;
    }
    __syncthreads();
    hist[t] = 0;
    __syncthreads();
#pragma unroll
    for (int i = 0; i < 16; ++i) {
        int e = base + t + i * 256;
        if (e < E) {
            int d = dst[e];
            int b = d >> 9;
            int slot = atomicAdd(&hist[b], 1);
            stage[abase[b] + slot] = (unsigned)src[e] | ((unsigned)(d & 511) << 17);
        }
    }
}

// --- B: per-bucket CSR finalize with padding-to-16 + sentinel fill ---
//     padded bucket base pb = bstart[b] + 7680*b (max pad 15/node * 512 nodes)
__global__ __launch_bounds__(256) void csr_build_kernel(const unsigned int* __restrict__ stage,
                                                        const int* __restrict__ bstart,
                                                        int* __restrict__ rowstart,
                                                        int* __restrict__ rowend,
                                                        float* __restrict__ dis,
                                                        int* __restrict__ csr_src, int N) {
    __shared__ int cnt[512];
    __shared__ int ofs[512];
    __shared__ int psum[256];
    __shared__ int tot;
    int b = blockIdx.x, t = threadIdx.x;
    int node0 = b << 9;
    int nb = min(512, N - node0);
    cnt[t] = 0;
    cnt[t + 256] = 0;
    __syncthreads();
    int eb = bstart[b], ee = bstart[b + 1];
    for (int e = eb + t; e < ee; e += 256) {
        unsigned w = stage[e];
        atomicAdd(&cnt[w >> 17], 1);
    }
    __syncthreads();
    int a = cnt[2 * t], c = cnt[2 * t + 1];
    int pa = (a + 15) & ~15, pc = (c + 15) & ~15;
    int ps = pa + pc;
    psum[t] = ps;
    __syncthreads();
    for (int off = 1; off < 256; off <<= 1) {
        int tmp = 0;
        if (t >= off) tmp = psum[t - off];
        __syncthreads();
        psum[t] += tmp;
        __syncthreads();
    }
    if (t == 255) tot = psum[255];
    int ex = psum[t] - ps;
    int pb = eb + 7680 * b;
    ofs[2 * t] = ex;
    ofs[2 * t + 1] = ex + pa;
    if (2 * t < nb) {
        rowstart[node0 + 2 * t] = pb + ex;
        rowend[node0 + 2 * t] = pb + ex + pa;
        dis[node0 + 2 * t] = rsqrtf(1.f + (float)a);
    }
    if (2 * t + 1 < nb) {
        rowstart[node0 + 2 * t + 1] = pb + ex + pa;
        rowend[node0 + 2 * t + 1] = pb + ex + pa + pc;
        dis[node0 + 2 * t + 1] = rsqrtf(1.f + (float)c);
    }
    __syncthreads();
    // sentinel pre-fill of the whole padded region
    int pt = tot;
    for (int i = t; i < pt; i += 256) csr_src[pb + i] = N;
    __syncthreads();
    // place real edges
    for (int e = eb + t; e < ee; e += 256) {
        unsigned w = stage[e];
        int l = w >> 17;
        int slot = atomicAdd(&ofs[l], 1);
        csr_src[pb + slot] = (int)(w & 0x1FFFFu);
    }
}

// --- register-blocked GEMM: C[M][NC] = X[M][K] @ W[K][NC] (+bias). ---
template <int K, int NC, bool IN_BF16, bool OUT_BF16>
__global__ __launch_bounds__(256) void gemm_kernel(const void* __restrict__ Xv,
                                                   const float* __restrict__ W,
                                                   const float* __restrict__ bias,
                                                   void* __restrict__ Cv, int M) {
    constexpr int TM = 128, KT = 32;
    constexpr int CL = NC / 8;      // col-lanes
    constexpr int RL = 256 / CL;    // row-lanes
    constexpr int RPT = TM / RL;    // rows per thread
    constexpr int XSTR = KT + 1;
    constexpr int WSTR = NC + 12;

    __shared__ float XL[TM * XSTR];
    __shared__ float WL[KT * WSTR];

    int tid = threadIdx.x;
    int tx = tid % CL, ty = tid / CL;
    int rowBase = blockIdx.x * TM;
    const int wgo = tx * 8 + ((tx >> 2) << 2);

    float4 acc0[RPT], acc1[RPT];
#pragma unroll
    for (int i = 0; i < RPT; ++i) {
        acc0[i] = make_float4(0.f, 0.f, 0.f, 0.f);
        acc1[i] = make_float4(0.f, 0.f, 0.f, 0.f);
    }

    for (int kk = 0; kk < K; kk += KT) {
        if (IN_BF16) {
            const unsigned short* Xb = (const unsigned short*)Xv;
#pragma unroll
            for (int q = 0; q < 2; ++q) {
                int li = q * 256 + tid;
                int r = li >> 2, c8 = (li & 3) * 8;
                int gr = rowBase + r;
                if (gr >= M) gr = M - 1;
                uint4 v = *(const uint4*)&Xb[(size_t)gr * K + kk + c8];
                float f[8];
                cvt8(v, f);
#pragma unroll
                for (int j = 0; j < 8; ++j) XL[r * XSTR + c8 + j] = f[j];
            }
        } else {
            const float* Xf = (const float*)Xv;
#pragma unroll
            for (int q = 0; q < 4; ++q) {
                int li = q * 256 + tid;
                int r = li >> 3, c4 = (li & 7) * 4;
                int gr = rowBase + r;
                if (gr >= M) gr = M - 1;
                float4 v = *(const float4*)&Xf[(size_t)gr * K + kk + c4];
                XL[r * XSTR + c4 + 0] = v.x;
                XL[r * XSTR + c4 + 1] = v.y;
                XL[r * XSTR + c4 + 2] = v.z;
                XL[r * XSTR + c4 + 3] = v.w;
            }
        }
        constexpr int WCH = KT * NC / 4 / 256;
#pragma unroll
        for (int q = 0; q < WCH; ++q) {
            int li = q * 256 + tid;
            int k = li / (NC / 4), c = (li % (NC / 4)) * 4;
            int g = c >> 3;
            float4 v = *(const float4*)&W[(size_t)(kk + k) * NC + c];
            *(float4*)&WL[k * WSTR + g * 8 + ((g >> 2) << 2) + (c & 7)] = v;
        }
        __syncthreads();
#pragma unroll
        for (int k = 0; k < KT; ++k) {
            float4 w0 = *(const float4*)&WL[k * WSTR + wgo];
            float4 w1 = *(const float4*)&WL[k * WSTR + wgo + 4];
            float xv[RPT];
#pragma unroll
            for (int i = 0; i < RPT; ++i) xv[i] = XL[(ty * RPT + i) * XSTR + k];
#pragma unroll
            for (int i = 0; i < RPT; ++i) {
                acc0[i].x += xv[i] * w0.x; acc0[i].y += xv[i] * w0.y;
                acc0[i].z += xv[i] * w0.z; acc0[i].w += xv[i] * w0.w;
                acc1[i].x += xv[i] * w1.x; acc1[i].y += xv[i] * w1.y;
                acc1[i].z += xv[i] * w1.z; acc1[i].w += xv[i] * w1.w;
            }
        }
        __syncthreads();
    }

    float4 b0 = make_float4(0.f, 0.f, 0.f, 0.f), b1 = b0;
    if (bias) {
        b0 = *(const float4*)&bias[tx * 8];
        b1 = *(const float4*)&bias[tx * 8 + 4];
    }
#pragma unroll
    for (int i = 0; i < RPT; ++i) {
        int gr = rowBase + ty * RPT + i;
        if (gr < M) {
            float4 v0 = acc0[i], v1 = acc1[i];
            v0.x += b0.x; v0.y += b0.y; v0.z += b0.z; v0.w += b0.w;
            v1.x += b1.x; v1.y += b1.y; v1.z += b1.z; v1.w += b1.w;
            if (OUT_BF16) {
                unsigned short* Cb = (unsigned short*)Cv;
                uint4 o;
                o.x = (unsigned)f2bf(v0.x) | ((unsigned)f2bf(v0.y) << 16);
                o.y = (unsigned)f2bf(v0.z) | ((unsigned)f2bf(v0.w) << 16);
                o.z = (unsigned)f2bf(v1.x) | ((unsigned)f2bf(v1.y) << 16);
                o.w = (unsigned)f2bf(v1.z) | ((unsigned)f2bf(v1.w) << 16);
                *(uint4*)&Cb[(size_t)gr * NC + tx * 8] = o;
            } else {
                float* Cf = (float*)Cv;
                *(float4*)&Cf[(size_t)gr * NC + tx * 8] = v0;
                *(float4*)&Cf[(size_t)gr * NC + tx * 8 + 4] = v1;
            }
        }
    }
}

// --- wave-per-node bf16 gather aggregation, branch-free padded edge lists ---
template <int NC>
__global__ __launch_bounds__(256) void aggregate_kernel(const unsigned short* __restrict__ h,
                                                        const float* __restrict__ dis,
                                                        const int* __restrict__ rowstart,
                                                        const int* __restrict__ rowend,
                                                        const int* __restrict__ csr_src,
                                                        const float* __restrict__ bias,
                                                        unsigned short* __restrict__ out,
                                                        int N) {
    constexpr int LPR = NC / 8;    // lanes per row (16 or 8)
    constexpr int RPS = 64 / LPR;  // rows per sub-step (4 or 8)
    constexpr int LD = 16 / RPS;   // gathers in flight (4 or 2)
    int wid = (blockIdx.x * blockDim.x + threadIdx.x) >> 6;
    int lane = threadIdx.x & 63;
    if (wid >= N) return;
    int n = wid;
    int sub = lane / LPR;
    int fid = lane % LPR;
    const uint4* h4 = (const uint4*)h;
    float d = dis[n];
    float acc[8];
#pragma unroll
    for (int i = 0; i < 8; ++i) acc[i] = 0.f;
    if (sub == 0) {
        uint4 hv = h4[n * LPR + fid];
        macc8(acc, hv, d);
    }

    int beg = rowstart[n], end = rowend[n];   // end-beg is a multiple of 16
    for (int e0 = beg; e0 < end; e0 += 64) {
        int idx = e0 + lane;
        int sv = N;
        float dv = 0.f;
        if (idx < end) { sv = csr_src[idx]; dv = dis[sv]; }
        int cnt = min(64, end - e0);          // multiple of 16
        for (int j = 0; j < cnt; j += 16) {
            int ss[LD];
            float cc[LD];
#pragma unroll
            for (int k = 0; k < LD; ++k) {
                int jj = j + k * RPS + sub;
                ss[k] = __shfl(sv, jj);
                cc[k] = __shfl(dv, jj);
            }
            uint4 vv[LD];
#pragma unroll
            for (int k = 0; k < LD; ++k) vv[k] = h4[ss[k] * LPR + fid];
#pragma unroll
            for (int k = 0; k < LD; ++k) macc8(acc, vv[k], cc[k]);
        }
    }
#pragma unroll
    for (int m = LPR; m < 64; m <<= 1) {
#pragma unroll
        for (int i = 0; i < 8; ++i) acc[i] += __shfl_xor(acc[i], m);
    }
    if (sub == 0) {
        const float4 bv0 = *(const float4*)&bias[fid * 8 + 0];
        const float4 bv1 = *(const float4*)&bias[fid * 8 + 4];
        float r[8];
        r[0] = fmaxf(acc[0] * d + bv0.x, 0.f);
        r[1] = fmaxf(acc[1] * d + bv0.y, 0.f);
        r[2] = fmaxf(acc[2] * d + bv0.z, 0.f);
        r[3] = fmaxf(acc[3] * d + bv0.w, 0.f);
        r[4] = fmaxf(acc[4] * d + bv1.x, 0.f);
        r[5] = fmaxf(acc[5] * d + bv1.y, 0.f);
        r[6] = fmaxf(acc[6] * d + bv1.z, 0.f);
        r[7] = fmaxf(acc[7] * d + bv1.w, 0.f);
        uint4 o;
        o.x = (unsigned)f2bf(r[0]) | ((unsigned)f2bf(r[1]) << 16);
        o.y = (unsigned)f2bf(r[2]) | ((unsigned)f2bf(r[3]) << 16);
        o.z = (unsigned)f2bf(r[4]) | ((unsigned)f2bf(r[5]) << 16);
        o.w = (unsigned)f2bf(r[6]) | ((unsigned)f2bf(r[7]) << 16);
        *(uint4*)&out[n * NC + fid * 8] = o;
    }
}

// --- segment-mean pool helpers (batch is sorted) ---
__global__ __launch_bounds__(128) void pool_kernel(const float* __restrict__ a1,
                                                   const int* __restrict__ batch,
                                                   float* __restrict__ gsum, int N) {
    int f = threadIdx.x;
    int n0 = blockIdx.x * 128;
    int nend = min(n0 + 128, N);
    float acc = 0.f;
    int gcur = batch[n0];
    for (int n = n0; n < nend; ++n) {
        int g = batch[n];
        if (g != gcur) {
            atomicAdd(&gsum[gcur * 128 + f], acc);
            acc = 0.f;
            gcur = g;
        }
        acc += a1[(size_t)n * 128 + f];
    }
    atomicAdd(&gsum[gcur * 128 + f], acc);
}

__global__ __launch_bounds__(256) void count_batch_kernel(const int* __restrict__ batch,
                                                          int* __restrict__ gcnt, int N) {
    __shared__ int lc[64];
    int t = threadIdx.x;
    if (t < 64) lc[t] = 0;
    __syncthreads();
    int n = blockIdx.x * blockDim.x + t;
    if (n < N) atomicAdd(&lc[batch[n]], 1);
    __syncthreads();
    if (t < 64 && lc[t] > 0) atomicAdd(&gcnt[t], lc[t]);
}

__global__ __launch_bounds__(128) void finalize_kernel(const float* __restrict__ gsum,
                                                       const int* __restrict__ gcnt,
                                                       const float* __restrict__ Wf2,
                                                       const float* __restrict__ bf2,
                                                       float* __restrict__ out) {
    __shared__ float red0[128], red1[128];
    int g = blockIdx.x, f = threadIdx.x;
    float cntf = (float)max(gcnt[g], 1);
    float ge = gsum[g * 128 + f] / cntf;
    out[g * 128 + f] = ge;
    red0[f] = ge * Wf2[f * 2 + 0];
    red1[f] = ge * Wf2[f * 2 + 1];
    __syncthreads();
    for (int off = 64; off > 0; off >>= 1) {
        if (f < off) { red0[f] += red0[f + off]; red1[f] += red1[f + off]; }
        __syncthreads();
    }
    if (f == 0) {
        out[8192 + 1 + g * 2 + 0] = red0[0] + bf2[0];
        out[8192 + 1 + g * 2 + 1] = red1[0] + bf2[1];
        if (g == 0) out[8192] = 0.f;
    }
}

extern "C" void kernel_launch(void* const* d_in, const int* in_sizes, int n_in,
                              void* d_out, int out_size, void* d_ws, size_t ws_size,
                              hipStream_t stream) {
    const float* x   = (const float*)d_in[0];
    const float* W1  = (const float*)d_in[1];
    const float* b1  = (const float*)d_in[2];
    const float* W2  = (const float*)d_in[3];
    const float* b2  = (const float*)d_in[4];
    const float* Wf1 = (const float*)d_in[5];
    const float* bf1 = (const float*)d_in[6];
    const float* Wf2 = (const float*)d_in[7];
    const float* bf2 = (const float*)d_in[8];
    const int* edge  = (const int*)d_in[9];
    const int* batch = (const int*)d_in[10];

    const int N = in_sizes[10];      // 100000
    const int E = in_sizes[9] / 2;   // 3200000
    const int* srcA = edge;
    const int* dstA = edge + E;
    float* out = (float*)d_out;

    const int NB = (N + 511) >> 9;   // buckets of 512 nodes

    char* p = (char*)d_ws;
    auto alloc = [&](size_t bytes) {
        char* r = p;
        p += (bytes + 255) & ~(size_t)255;
        return r;
    };
    float* gsum     = (float*)alloc(64 * 128 * 4);
    int*   gcnt     = (int*)alloc(64 * 4);
    int*   bcount   = (int*)alloc(256 * 4);
    int*   bfill    = (int*)alloc(256 * 4);
    size_t zbytes   = (size_t)(p - (char*)d_ws);
    int*   bstart   = (int*)alloc(260 * 4);
    float* dis      = (float*)alloc((size_t)(N + 1) * 4);
    int*   rowstart = (int*)alloc((size_t)N * 4);
    int*   rowend   = (int*)alloc((size_t)N * 4);
    unsigned int* stage = (unsigned int*)alloc((size_t)E * 4);
    int*   csr_src  = (int*)alloc(((size_t)E + 7680 * (size_t)NB) * 4);
    float* bufA     = (float*)alloc(((size_t)N + 1) * 128 * 4);  // h/g (bf16) then a1 (f32)
    float* bufB     = (float*)alloc(((size_t)N + 1) * 128 * 2);  // h1/h2 (bf16)

    unsigned short* bufAb = (unsigned short*)bufA;
    unsigned short* bufBb = (unsigned short*)bufB;

    hipMemsetAsync(d_ws, 0, zbytes, stream);

    const int EB = (E + 4095) / 4096;
    bucket_hist_kernel<<<EB, 256, 0, stream>>>(dstA, bcount, E);
    bucket_scan_kernel<<<1, 256, 0, stream>>>(bcount, bstart, dis, NB, N);
    bucket_scatter_kernel<<<EB, 256, 0, stream>>>(srcA, dstA, bstart, bfill, stage, E);
    csr_build_kernel<<<NB, 256, 0, stream>>>(stage, bstart, rowstart, rowend, dis,
                                             csr_src, N);

    const int GB = (N + 127) / 128;
    // layer 1: h = x@W1 (bf16) ; h1 = relu(d*(sum dis_s*h_s + d*h_n) + b1) (bf16)
    gemm_kernel<128, 128, false, true><<<GB, 256, 0, stream>>>(x, W1, nullptr, bufAb, N);
    aggregate_kernel<128><<<(N + 3) / 4, 256, 0, stream>>>(bufAb, dis, rowstart, rowend,
                                                           csr_src, b1, bufBb, N);
    // layer 2
    gemm_kernel<128, 64, true, true><<<GB, 256, 0, stream>>>(bufBb, W2, nullptr, bufAb, N);
    aggregate_kernel<64><<<(N + 3) / 4, 256, 0, stream>>>(bufAb, dis, rowstart, rowend,
                                                          csr_src, b2, bufBb, N);
    // head: a1 = h2@Wf1 + bf1 (fp32)
    gemm_kernel<64, 128, true, false><<<GB, 256, 0, stream>>>(bufBb, Wf1, bf1, bufA, N);

    pool_kernel<<<(N + 127) / 128, 128, 0, stream>>>(bufA, batch, gsum, N);
    count_batch_kernel<<<(N + 255) / 256, 256, 0, stream>>>(batch, gcnt, N);
    finalize_kernel<<<64, 128, 0, stream>>>(gsum, gcnt, Wf2, bf2, out);
}